// Round 1
// baseline (245.349 us; speedup 1.0000x reference)
//
#include <hip/hip_runtime.h>
#include <hip/hip_bf16.h>
#include <math.h>

// Problem constants (fixed by setup_inputs): gts/preds [4, 8192, 3] fp32.
#define BB 4
#define NPTS 8192
#define THREADS 256
#define CHUNKS (NPTS / THREADS)   // 32 query chunks per (dir, batch)

// ---------------------------------------------------------------------------
// Kernel 1: pack points as float4 [x, y, z, x^2+y^2+z^2].
// Layout in ws: packed[set][b][i], set 0 = gts, set 1 = preds.
// ---------------------------------------------------------------------------
__global__ void pack_kernel(const float* __restrict__ gts,
                            const float* __restrict__ preds,
                            float4* __restrict__ packed) {
    int idx = blockIdx.x * blockDim.x + threadIdx.x;   // 0 .. 2*BB*NPTS-1
    if (idx >= 2 * BB * NPTS) return;
    int set  = idx / (BB * NPTS);
    int pidx = idx - set * (BB * NPTS);
    const float* src = set ? preds : gts;
    float x = src[pidx * 3 + 0];
    float y = src[pidx * 3 + 1];
    float z = src[pidx * 3 + 2];
    packed[idx] = make_float4(x, y, z, fmaf(x, x, fmaf(y, y, z * z)));
}

// ---------------------------------------------------------------------------
// Kernel 2: one-directional chamfer partial sums.
// blockIdx.x encodes (dir, b, chunk). dir=0: queries=preds, refs=gts (loss_1);
// dir=1: queries=gts, refs=preds (loss_2).
// Each thread owns one query point, loops over all 8192 refs via wave-uniform
// (scalar) float4 loads, tracking min of (rr - 2*dot) in 4 accumulators.
// ---------------------------------------------------------------------------
__global__ __launch_bounds__(THREADS) void
chamfer_kernel(const float4* __restrict__ packed, float* __restrict__ partials) {
    int blk   = blockIdx.x;
    int dir   = blk / (BB * CHUNKS);
    int rem   = blk - dir * (BB * CHUNKS);
    int b     = rem / CHUNKS;
    int chunk = rem - b * CHUNKS;

    const float4* qbase = packed + (dir == 0 ? 1 : 0) * (BB * NPTS) + b * NPTS;
    const float4* rbase = packed + (dir == 0 ? 0 : 1) * (BB * NPTS) + b * NPTS;

    int qi = chunk * THREADS + threadIdx.x;
    float4 q = qbase[qi];
    float qx = q.x, qy = q.y, qz = q.z, qq = q.w;

    const float INF = 3.0e38f;
    float m0 = INF, m1 = INF, m2 = INF, m3 = INF;

    #pragma unroll 4
    for (int j = 0; j < NPTS; j += 4) {
        float4 r0 = rbase[j + 0];
        float4 r1 = rbase[j + 1];
        float4 r2 = rbase[j + 2];
        float4 r3 = rbase[j + 3];
        float t0 = fmaf(-2.0f, fmaf(qz, r0.z, fmaf(qy, r0.y, qx * r0.x)), r0.w);
        float t1 = fmaf(-2.0f, fmaf(qz, r1.z, fmaf(qy, r1.y, qx * r1.x)), r1.w);
        float t2 = fmaf(-2.0f, fmaf(qz, r2.z, fmaf(qy, r2.y, qx * r2.x)), r2.w);
        float t3 = fmaf(-2.0f, fmaf(qz, r3.z, fmaf(qy, r3.y, qx * r3.x)), r3.w);
        m0 = fminf(m0, t0);
        m1 = fminf(m1, t1);
        m2 = fminf(m2, t2);
        m3 = fminf(m3, t3);
    }

    float m = fminf(fminf(m0, m1), fminf(m2, m3));
    float d = sqrtf(fmaxf(qq + m, 0.0f));

    // Block-wide sum: wave shuffle reduce, then LDS across the 4 waves.
    float sum = d;
    #pragma unroll
    for (int off = 32; off > 0; off >>= 1)
        sum += __shfl_down(sum, off, 64);

    __shared__ float wsum[THREADS / 64];
    int lane = threadIdx.x & 63;
    int wid  = threadIdx.x >> 6;
    if (lane == 0) wsum[wid] = sum;
    __syncthreads();
    if (threadIdx.x == 0)
        partials[blk] = wsum[0] + wsum[1] + wsum[2] + wsum[3];
}

// ---------------------------------------------------------------------------
// Kernel 3: reduce 2*BB*CHUNKS partials -> out[b] (overwrites, no zero-init
// needed; d_out is poisoned before every timed call).
// ---------------------------------------------------------------------------
__global__ void finalize_kernel(const float* __restrict__ partials,
                                float* __restrict__ out) {
    int b = threadIdx.x;
    if (b < BB) {
        float s = 0.0f;
        #pragma unroll
        for (int dir = 0; dir < 2; ++dir)
            for (int c = 0; c < CHUNKS; ++c)
                s += partials[dir * BB * CHUNKS + b * CHUNKS + c];
        out[b] = s;
    }
}

extern "C" void kernel_launch(void* const* d_in, const int* in_sizes, int n_in,
                              void* d_out, int out_size, void* d_ws, size_t ws_size,
                              hipStream_t stream) {
    const float* gts   = (const float*)d_in[0];
    const float* preds = (const float*)d_in[1];
    float* out = (float*)d_out;

    // ws layout: [packed: 2*BB*NPTS float4 = 1 MiB][partials: 2*BB*CHUNKS floats]
    float4* packed   = (float4*)d_ws;
    float*  partials = (float*)((char*)d_ws + 2 * BB * NPTS * sizeof(float4));

    int total_pack = 2 * BB * NPTS;
    pack_kernel<<<(total_pack + THREADS - 1) / THREADS, THREADS, 0, stream>>>(
        gts, preds, packed);

    int nblocks = 2 * BB * CHUNKS;   // 256
    chamfer_kernel<<<nblocks, THREADS, 0, stream>>>(packed, partials);

    finalize_kernel<<<1, 64, 0, stream>>>(partials, out);
}

// Round 2
// 136.383 us; speedup vs baseline: 1.7990x; 1.7990x over previous
//
#include <hip/hip_runtime.h>
#include <hip/hip_bf16.h>
#include <math.h>

// Problem constants (fixed by setup_inputs): gts/preds [4, 8192, 3] fp32.
#define BB 4
#define NPTS 8192
#define THREADS 256
#define CHUNKS (NPTS / THREADS)     // 32 query chunks per (dir, batch)
#define SLICES 8                    // split of the ref dimension (occupancy)
#define REFS_PER_SLICE (NPTS / SLICES)   // 1024
#define NQ_TOTAL (2 * BB * NPTS)    // 65536 (dir, b, q) query points

// ws layout:
//   [0, 1 MiB)            packed: 2*BB*NPTS float4 [x,y,z,|p|^2], set0=gts set1=preds
//   [1 MiB, 3 MiB)        minpart: SLICES * NQ_TOTAL floats (partial min of rr-2*dot)
//   [3 MiB, +1 KiB)       partials: 2*BB*CHUNKS floats

// ---------------------------------------------------------------------------
// Kernel 1: pack points as float4 [x, y, z, x^2+y^2+z^2].
// ---------------------------------------------------------------------------
__global__ void pack_kernel(const float* __restrict__ gts,
                            const float* __restrict__ preds,
                            float4* __restrict__ packed) {
    int idx = blockIdx.x * blockDim.x + threadIdx.x;   // 0 .. 2*BB*NPTS-1
    if (idx >= 2 * BB * NPTS) return;
    int set  = idx / (BB * NPTS);
    int pidx = idx - set * (BB * NPTS);
    const float* src = set ? preds : gts;
    float x = src[pidx * 3 + 0];
    float y = src[pidx * 3 + 1];
    float z = src[pidx * 3 + 2];
    packed[idx] = make_float4(x, y, z, fmaf(x, x, fmaf(y, y, z * z)));
}

// ---------------------------------------------------------------------------
// Kernel 2: partial min over one ref slice.
// blockIdx.x encodes (slice, dir, b, chunk). Each thread owns one query,
// scans REFS_PER_SLICE refs via wave-uniform (scalar) float4 loads, tracks
// min of (rr - 2*dot) in 4 accumulators, writes one float (coalesced).
// ---------------------------------------------------------------------------
__global__ __launch_bounds__(THREADS) void
chamfer_min_kernel(const float4* __restrict__ packed,
                   float* __restrict__ minpart) {
    int blk   = blockIdx.x;
    int slice = blk / (2 * BB * CHUNKS);
    int rem   = blk - slice * (2 * BB * CHUNKS);
    int dir   = rem / (BB * CHUNKS);
    rem       = rem - dir * (BB * CHUNKS);
    int b     = rem / CHUNKS;
    int chunk = rem - b * CHUNKS;

    const float4* qbase = packed + (dir == 0 ? 1 : 0) * (BB * NPTS) + b * NPTS;
    const float4* rbase = packed + (dir == 0 ? 0 : 1) * (BB * NPTS) + b * NPTS
                        + slice * REFS_PER_SLICE;

    int qi = chunk * THREADS + threadIdx.x;
    float4 q = qbase[qi];
    float qx = q.x, qy = q.y, qz = q.z;

    const float INF = 3.0e38f;
    float m0 = INF, m1 = INF, m2 = INF, m3 = INF;

    #pragma unroll 4
    for (int j = 0; j < REFS_PER_SLICE; j += 4) {
        float4 r0 = rbase[j + 0];
        float4 r1 = rbase[j + 1];
        float4 r2 = rbase[j + 2];
        float4 r3 = rbase[j + 3];
        float t0 = fmaf(-2.0f, fmaf(qz, r0.z, fmaf(qy, r0.y, qx * r0.x)), r0.w);
        float t1 = fmaf(-2.0f, fmaf(qz, r1.z, fmaf(qy, r1.y, qx * r1.x)), r1.w);
        float t2 = fmaf(-2.0f, fmaf(qz, r2.z, fmaf(qy, r2.y, qx * r2.x)), r2.w);
        float t3 = fmaf(-2.0f, fmaf(qz, r3.z, fmaf(qy, r3.y, qx * r3.x)), r3.w);
        m0 = fminf(m0, t0);
        m1 = fminf(m1, t1);
        m2 = fminf(m2, t2);
        m3 = fminf(m3, t3);
    }

    float m = fminf(fminf(m0, m1), fminf(m2, m3));
    // minpart[slice][dir*BB+b][q within batch]
    int dirb = dir * BB + b;
    minpart[slice * NQ_TOTAL + dirb * NPTS + qi] = m;
}

// ---------------------------------------------------------------------------
// Kernel 3: merge slices, add |q|^2, sqrt, block-reduce sum.
// grid = 2*BB*CHUNKS blocks of 256.
// ---------------------------------------------------------------------------
__global__ __launch_bounds__(THREADS) void
chamfer_merge_kernel(const float4* __restrict__ packed,
                     const float* __restrict__ minpart,
                     float* __restrict__ partials) {
    int blk   = blockIdx.x;              // 0 .. 2*BB*CHUNKS-1
    int dir   = blk / (BB * CHUNKS);
    int rem   = blk - dir * (BB * CHUNKS);
    int b     = rem / CHUNKS;
    int chunk = rem - b * CHUNKS;

    int qi   = chunk * THREADS + threadIdx.x;
    int dirb = dir * BB + b;

    float m = 3.0e38f;
    #pragma unroll
    for (int s = 0; s < SLICES; ++s)
        m = fminf(m, minpart[s * NQ_TOTAL + dirb * NPTS + qi]);

    float qq = packed[(dir == 0 ? 1 : 0) * (BB * NPTS) + b * NPTS + qi].w;
    float d = sqrtf(fmaxf(qq + m, 0.0f));

    // Block-wide sum: wave shuffle reduce, then LDS across the 4 waves.
    float sum = d;
    #pragma unroll
    for (int off = 32; off > 0; off >>= 1)
        sum += __shfl_down(sum, off, 64);

    __shared__ float wsum[THREADS / 64];
    int lane = threadIdx.x & 63;
    int wid  = threadIdx.x >> 6;
    if (lane == 0) wsum[wid] = sum;
    __syncthreads();
    if (threadIdx.x == 0)
        partials[blk] = wsum[0] + wsum[1] + wsum[2] + wsum[3];
}

// ---------------------------------------------------------------------------
// Kernel 4: reduce 2*BB*CHUNKS partials -> out[b].
// ---------------------------------------------------------------------------
__global__ void finalize_kernel(const float* __restrict__ partials,
                                float* __restrict__ out) {
    int b = threadIdx.x;
    if (b < BB) {
        float s = 0.0f;
        #pragma unroll
        for (int dir = 0; dir < 2; ++dir)
            for (int c = 0; c < CHUNKS; ++c)
                s += partials[(dir * BB + b) * CHUNKS + c];
        out[b] = s;
    }
}

extern "C" void kernel_launch(void* const* d_in, const int* in_sizes, int n_in,
                              void* d_out, int out_size, void* d_ws, size_t ws_size,
                              hipStream_t stream) {
    const float* gts   = (const float*)d_in[0];
    const float* preds = (const float*)d_in[1];
    float* out = (float*)d_out;

    float4* packed   = (float4*)d_ws;
    float*  minpart  = (float*)((char*)d_ws + (size_t)NQ_TOTAL * sizeof(float4));
    float*  partials = minpart + (size_t)SLICES * NQ_TOTAL;

    int total_pack = NQ_TOTAL;
    pack_kernel<<<(total_pack + THREADS - 1) / THREADS, THREADS, 0, stream>>>(
        gts, preds, packed);

    int nblocks_min = SLICES * 2 * BB * CHUNKS;   // 2048
    chamfer_min_kernel<<<nblocks_min, THREADS, 0, stream>>>(packed, minpart);

    int nblocks_merge = 2 * BB * CHUNKS;          // 256
    chamfer_merge_kernel<<<nblocks_merge, THREADS, 0, stream>>>(packed, minpart,
                                                                partials);

    finalize_kernel<<<1, 64, 0, stream>>>(partials, out);
}

// Round 3
// 124.945 us; speedup vs baseline: 1.9636x; 1.0915x over previous
//
#include <hip/hip_runtime.h>
#include <hip/hip_bf16.h>
#include <math.h>

// Problem constants (fixed by setup_inputs): gts/preds [4, 8192, 3] fp32.
#define BB 4
#define NPTS 8192
#define THREADS 256
#define QPT 2                         // queries per thread
#define QPB (THREADS * QPT)           // 512 queries per block
#define CHUNKSQ (NPTS / QPB)          // 16 query chunks per (dir, b)
#define SLICES 16                     // split of the ref dimension
#define REFS_PER_SLICE (NPTS / SLICES)  // 512
#define NQ_TOTAL (2 * BB * NPTS)      // 65536 (dir, b, q) query points

// ws layout:
//   [0, 1 MiB)      packed: 2*BB*NPTS float4 [x,y,z,|p|^2], set0=gts set1=preds
//   [1 MiB, 5 MiB)  minpart: SLICES * NQ_TOTAL floats (partial min of rr-2*q.r)

// ---------------------------------------------------------------------------
// Kernel 1: pack points as float4 [x, y, z, x^2+y^2+z^2]; also zero out[].
// ---------------------------------------------------------------------------
__global__ void pack_kernel(const float* __restrict__ gts,
                            const float* __restrict__ preds,
                            float4* __restrict__ packed,
                            float* __restrict__ out) {
    if (blockIdx.x == 0 && threadIdx.x < BB) out[threadIdx.x] = 0.0f;
    int idx = blockIdx.x * blockDim.x + threadIdx.x;   // 0 .. 2*BB*NPTS-1
    if (idx >= 2 * BB * NPTS) return;
    int set  = idx / (BB * NPTS);
    int pidx = idx - set * (BB * NPTS);
    const float* src = set ? preds : gts;
    float x = src[pidx * 3 + 0];
    float y = src[pidx * 3 + 1];
    float z = src[pidx * 3 + 2];
    packed[idx] = make_float4(x, y, z, fmaf(x, x, fmaf(y, y, z * z)));
}

// ---------------------------------------------------------------------------
// Kernel 2: partial min over one ref slice; 2 queries per thread.
// blockIdx.x encodes (slice, dir, b, chunk). Refs are read via wave-uniform
// addresses -> scalar s_load_dwordx4; inner body is 3 fma + 1 min per pair
// (the -2 factor is folded into the per-thread query registers).
// ---------------------------------------------------------------------------
__global__ __launch_bounds__(THREADS) void
chamfer_min_kernel(const float4* __restrict__ packed,
                   float* __restrict__ minpart) {
    int blk   = blockIdx.x;
    int slice = blk / (2 * BB * CHUNKSQ);
    int rem   = blk - slice * (2 * BB * CHUNKSQ);
    int dir   = rem / (BB * CHUNKSQ);
    rem       = rem - dir * (BB * CHUNKSQ);
    int b     = rem / CHUNKSQ;
    int chunk = rem - b * CHUNKSQ;

    const float4* qbase = packed + (dir == 0 ? 1 : 0) * (BB * NPTS) + b * NPTS;
    const float4* rbase = packed + (dir == 0 ? 0 : 1) * (BB * NPTS) + b * NPTS
                        + slice * REFS_PER_SLICE;

    int qi0 = chunk * QPB + threadIdx.x;
    int qi1 = qi0 + THREADS;
    float4 qa = qbase[qi0];
    float4 qb = qbase[qi1];
    float ax = -2.0f * qa.x, ay = -2.0f * qa.y, az = -2.0f * qa.z;
    float bx = -2.0f * qb.x, by = -2.0f * qb.y, bz = -2.0f * qb.z;

    const float INF = 3.0e38f;
    float a0 = INF, a1 = INF, a2 = INF, a3 = INF;
    float b0 = INF, b1 = INF, b2 = INF, b3 = INF;

    #pragma unroll 2
    for (int j = 0; j < REFS_PER_SLICE; j += 4) {
        float4 r0 = rbase[j + 0];
        float4 r1 = rbase[j + 1];
        float4 r2 = rbase[j + 2];
        float4 r3 = rbase[j + 3];
        float ta0 = fmaf(ax, r0.x, fmaf(ay, r0.y, fmaf(az, r0.z, r0.w)));
        float ta1 = fmaf(ax, r1.x, fmaf(ay, r1.y, fmaf(az, r1.z, r1.w)));
        float ta2 = fmaf(ax, r2.x, fmaf(ay, r2.y, fmaf(az, r2.z, r2.w)));
        float ta3 = fmaf(ax, r3.x, fmaf(ay, r3.y, fmaf(az, r3.z, r3.w)));
        float tb0 = fmaf(bx, r0.x, fmaf(by, r0.y, fmaf(bz, r0.z, r0.w)));
        float tb1 = fmaf(bx, r1.x, fmaf(by, r1.y, fmaf(bz, r1.z, r1.w)));
        float tb2 = fmaf(bx, r2.x, fmaf(by, r2.y, fmaf(bz, r2.z, r2.w)));
        float tb3 = fmaf(bx, r3.x, fmaf(by, r3.y, fmaf(bz, r3.z, r3.w)));
        a0 = fminf(a0, ta0);  a1 = fminf(a1, ta1);
        a2 = fminf(a2, ta2);  a3 = fminf(a3, ta3);
        b0 = fminf(b0, tb0);  b1 = fminf(b1, tb1);
        b2 = fminf(b2, tb2);  b3 = fminf(b3, tb3);
    }

    float ma = fminf(fminf(a0, a1), fminf(a2, a3));
    float mb = fminf(fminf(b0, b1), fminf(b2, b3));

    int dirb = dir * BB + b;
    minpart[slice * NQ_TOTAL + dirb * NPTS + qi0] = ma;
    minpart[slice * NQ_TOTAL + dirb * NPTS + qi1] = mb;
}

// ---------------------------------------------------------------------------
// Kernel 3: merge slices, add |q|^2, sqrt, block-reduce, atomicAdd to out[b].
// grid = NQ_TOTAL / THREADS = 256 blocks; each block lies within one (dir,b).
// ---------------------------------------------------------------------------
__global__ __launch_bounds__(THREADS) void
chamfer_merge_kernel(const float4* __restrict__ packed,
                     const float* __restrict__ minpart,
                     float* __restrict__ out) {
    int q      = blockIdx.x * THREADS + threadIdx.x;   // 0 .. NQ_TOTAL-1
    int dirb   = q / NPTS;
    int qlocal = q - dirb * NPTS;
    int dir    = dirb / BB;
    int b      = dirb - dir * BB;

    float m = 3.0e38f;
    #pragma unroll
    for (int s = 0; s < SLICES; ++s)
        m = fminf(m, minpart[s * NQ_TOTAL + q]);

    float qq = packed[(dir == 0 ? 1 : 0) * (BB * NPTS) + b * NPTS + qlocal].w;
    float d = sqrtf(fmaxf(qq + m, 0.0f));

    // Block-wide sum: wave shuffle reduce, then LDS across the 4 waves.
    float sum = d;
    #pragma unroll
    for (int off = 32; off > 0; off >>= 1)
        sum += __shfl_down(sum, off, 64);

    __shared__ float wsum[THREADS / 64];
    int lane = threadIdx.x & 63;
    int wid  = threadIdx.x >> 6;
    if (lane == 0) wsum[wid] = sum;
    __syncthreads();
    if (threadIdx.x == 0)
        atomicAdd(out + b, wsum[0] + wsum[1] + wsum[2] + wsum[3]);
}

extern "C" void kernel_launch(void* const* d_in, const int* in_sizes, int n_in,
                              void* d_out, int out_size, void* d_ws, size_t ws_size,
                              hipStream_t stream) {
    const float* gts   = (const float*)d_in[0];
    const float* preds = (const float*)d_in[1];
    float* out = (float*)d_out;

    float4* packed  = (float4*)d_ws;
    float*  minpart = (float*)((char*)d_ws + (size_t)NQ_TOTAL * sizeof(float4));

    pack_kernel<<<(NQ_TOTAL + THREADS - 1) / THREADS, THREADS, 0, stream>>>(
        gts, preds, packed, out);

    int nblocks_min = SLICES * 2 * BB * CHUNKSQ;   // 2048
    chamfer_min_kernel<<<nblocks_min, THREADS, 0, stream>>>(packed, minpart);

    int nblocks_merge = NQ_TOTAL / THREADS;        // 256
    chamfer_merge_kernel<<<nblocks_merge, THREADS, 0, stream>>>(packed, minpart,
                                                                out);
}